// Round 1
// baseline (171.610 us; speedup 1.0000x reference)
//
#include <hip/hip_runtime.h>
#include <math.h>

constexpr int D    = 64;
constexpr int TILE = 64;
constexpr int PAD  = 68;   // row stride in floats: 16B-aligned (68*4=272), spreads banks

__global__ __launch_bounds__(256) void cosgauss_kernel(
    const float* __restrict__ x, const float* __restrict__ y,
    const float* __restrict__ mu, const float* __restrict__ ls2,
    float* __restrict__ out, int N, int M)
{
    __shared__ float xs[TILE][PAD];
    __shared__ float ys[TILE][PAD];
    __shared__ float musc[D];                 // mu[d] / s_sqrt[d]
    __shared__ float sx2[TILE], smx[TILE], sy2[TILE], smy[TILE];

    const int b  = blockIdx.z;
    const int n0 = blockIdx.y * TILE;
    const int m0 = blockIdx.x * TILE;
    const int t  = threadIdx.x;

    const int cc = t & 15;    // column group -> cols cc*4 .. cc*4+3
    const int rr = t >> 4;    // 0..15 -> rows rr*4 .. rr*4+3
    const int c4 = cc * 4;

    // per-column sqrt scales (s_sqrt = exp(0.5*logs2diag))
    const float s0 = __expf(0.5f * ls2[c4 + 0]);
    const float s1 = __expf(0.5f * ls2[c4 + 1]);
    const float s2 = __expf(0.5f * ls2[c4 + 2]);
    const float s3 = __expf(0.5f * ls2[c4 + 3]);

    const float* xb = x + ((size_t)b * N + n0) * D;
    const float* yb = y + ((size_t)b * M + m0) * D;

    // ---- stage scaled tiles into LDS (coalesced float4 loads) ----
    #pragma unroll
    for (int r = 0; r < 4; ++r) {
        const int row = rr * 4 + r;
        const float4 vx = *(const float4*)(xb + row * D + c4);
        const float4 vy = *(const float4*)(yb + row * D + c4);
        xs[row][c4 + 0] = vx.x * s0;
        xs[row][c4 + 1] = vx.y * s1;
        xs[row][c4 + 2] = vx.z * s2;
        xs[row][c4 + 3] = vx.w * s3;
        ys[row][c4 + 0] = vy.x * s0;
        ys[row][c4 + 1] = vy.y * s1;
        ys[row][c4 + 2] = vy.z * s2;
        ys[row][c4 + 3] = vy.w * s3;
    }
    if (t < D) {
        // mx = sum_d raw_x*mu = sum_d (x*s)*(mu/s)
        musc[t] = mu[t] * __expf(-0.5f * ls2[t]);
    }
    __syncthreads();

    // ---- per-row stats: x2, x.mu (rows) and y2, y.mu (cols) ----
    if (t < 64) {
        float a2 = 0.f, am = 0.f;
        #pragma unroll
        for (int d4 = 0; d4 < D; d4 += 4) {
            const float4 v  = *(const float4*)&xs[t][d4];
            const float4 m4 = *(const float4*)&musc[d4];
            a2 += v.x * v.x + v.y * v.y + v.z * v.z + v.w * v.w;
            am += v.x * m4.x + v.y * m4.y + v.z * m4.z + v.w * m4.w;
        }
        sx2[t] = a2; smx[t] = am;
    } else if (t < 128) {
        const int r2 = t - 64;
        float a2 = 0.f, am = 0.f;
        #pragma unroll
        for (int d4 = 0; d4 < D; d4 += 4) {
            const float4 v  = *(const float4*)&ys[r2][d4];
            const float4 m4 = *(const float4*)&musc[d4];
            a2 += v.x * v.x + v.y * v.y + v.z * v.z + v.w * v.w;
            am += v.x * m4.x + v.y * m4.y + v.z * m4.z + v.w * m4.w;
        }
        sy2[r2] = a2; smy[r2] = am;
    }
    __syncthreads();

    // ---- main dot-product loop: 4x4 micro-tile per thread ----
    const int tx = t & 15;   // output cols m_local = tx + 16*j
    const int ty = t >> 4;   // output rows n_local = ty + 16*i

    float acc[4][4] = {};
    #pragma unroll
    for (int d = 0; d < D; d += 4) {
        float4 a4[4], b4[4];
        #pragma unroll
        for (int i = 0; i < 4; ++i) a4[i] = *(const float4*)&xs[ty + 16 * i][d];
        #pragma unroll
        for (int j = 0; j < 4; ++j) b4[j] = *(const float4*)&ys[tx + 16 * j][d];
        #pragma unroll
        for (int i = 0; i < 4; ++i)
            #pragma unroll
            for (int j = 0; j < 4; ++j) {
                acc[i][j] += a4[i].x * b4[j].x;
                acc[i][j] += a4[i].y * b4[j].y;
                acc[i][j] += a4[i].z * b4[j].z;
                acc[i][j] += a4[i].w * b4[j].w;
            }
    }

    // ---- epilogue: cos(mx-my) * exp(-0.5*sqd) ----
    constexpr float INV2PI = 0.15915494309189535f;
    #pragma unroll
    for (int i = 0; i < 4; ++i) {
        const int nl = ty + 16 * i;
        float* orow = out + ((size_t)b * N + (n0 + nl)) * (size_t)M + m0;
        const float x2v = sx2[nl];
        const float mxv = smx[nl];
        #pragma unroll
        for (int j = 0; j < 4; ++j) {
            const int ml = tx + 16 * j;
            float sqd = fmaxf(x2v + sy2[ml] - 2.0f * acc[i][j], 0.0f);
            float arg = mxv - smy[ml];
            // cos via revolutions + hw v_cos (|arg| <= ~40, reduction err ~4e-6 abs)
            float r = arg * INV2PI;
            r -= floorf(r);
#if __has_builtin(__builtin_amdgcn_cosf)
            float cosv = __builtin_amdgcn_cosf(r);
#else
            float cosv = __cosf(arg);
#endif
            float e = __expf(-0.5f * sqd);
            orow[ml] = cosv * e;
        }
    }
}

extern "C" void kernel_launch(void* const* d_in, const int* in_sizes, int n_in,
                              void* d_out, int out_size, void* d_ws, size_t ws_size,
                              hipStream_t stream)
{
    const float* x   = (const float*)d_in[0];
    const float* y   = (const float*)d_in[1];
    const float* mu  = (const float*)d_in[2];
    const float* ls2 = (const float*)d_in[3];
    float* out = (float*)d_out;

    const int Dd = in_sizes[3];                         // 64
    const long long BN = in_sizes[0] / Dd;              // B*N
    const long long BM = in_sizes[1] / Dd;              // B*M
    const int B = (int)((BN * BM) / (long long)out_size);
    const int N = (int)(BN / B);
    const int M = (int)(BM / B);

    dim3 grid(M / TILE, N / TILE, B);
    dim3 block(256);
    hipLaunchKernelGGL(cosgauss_kernel, grid, block, 0, stream,
                       x, y, mu, ls2, out, N, M);
}